// Round 19
// baseline (2078.106 us; speedup 1.0000x reference)
//
#include <hip/hip_runtime.h>
#include <hip/hip_bf16.h>
#include <math.h>
#include <stdint.h>

typedef __hip_bfloat16 bf16;
typedef __attribute__((ext_vector_type(8))) short bf16x8;   // 8 bf16 = 4 VGPR
typedef __attribute__((ext_vector_type(4))) float f32x4;

#define DEV_INLINE __device__ __forceinline__

DEV_INLINE float wred_sum(float v) {
    #pragma unroll
    for (int o = 32; o > 0; o >>= 1) v += __shfl_xor(v, o);
    return v;
}
DEV_INLINE float red16_max(float v) {
    v = fmaxf(v, __shfl_xor(v, 1)); v = fmaxf(v, __shfl_xor(v, 2));
    v = fmaxf(v, __shfl_xor(v, 4)); v = fmaxf(v, __shfl_xor(v, 8));
    return v;
}
DEV_INLINE float red16_sum(float v) {
    v += __shfl_xor(v, 1); v += __shfl_xor(v, 2);
    v += __shfl_xor(v, 4); v += __shfl_xor(v, 8);
    return v;
}
DEV_INLINE float gelu_tanh(float v) {
    float t = tanhf(0.7978845608028654f * (v + 0.044715f * v * v * v));
    return 0.5f * v * (1.f + t);
}
DEV_INLINE float silu(float v) { return v / (1.f + expf(-v)); }
DEV_INLINE short f2bs(float f) { bf16 h = __float2bfloat16(f); short s; __builtin_memcpy(&s, &h, 2); return s; }

typedef const __attribute__((address_space(1))) uint32_t* gptr_t;
typedef __attribute__((address_space(3))) uint32_t* lptr_t;

DEV_INLINE void gload_lds16(const bf16* gp, bf16* lp) {
    __builtin_amdgcn_global_load_lds((gptr_t)gp, (lptr_t)lp, 16, 0, 0);
}

// counted-vmcnt barrier: wait own loads down to N outstanding, then s_barrier.
#define WAITBAR8() asm volatile("s_waitcnt vmcnt(8)\ns_barrier" ::: "memory")
#define WAITBAR4() asm volatile("s_waitcnt vmcnt(4)\ns_barrier" ::: "memory")
#define WAITBAR0() asm volatile("s_waitcnt vmcnt(0)\ns_barrier" ::: "memory")

// bijective XCD-chunk swizzle (m204)
DEV_INLINE int xcd_swz(int wg, int nwg) {
    int q = nwg >> 3, r = nwg & 7;
    int xcd = wg & 7, pos = wg >> 3;
    return (xcd < r ? xcd * (q + 1) : r * (q + 1) + (xcd - r) * q) + pos;
}

// ---------------------------------------------------------------------------
// fp32 -> bf16 conversion, 8 elems/thread, n multiple of 8
// ---------------------------------------------------------------------------
__global__ void cvt_bf16(const float* __restrict__ in, bf16* __restrict__ out, long n) {
    long i = ((long)blockIdx.x * blockDim.x + threadIdx.x) * 8;
    if (i >= n) return;
    float4 a = *(const float4*)(in + i);
    float4 b = *(const float4*)(in + i + 4);
    bf16x8 v;
    v[0] = f2bs(a.x); v[1] = f2bs(a.y); v[2] = f2bs(a.z); v[3] = f2bs(a.w);
    v[4] = f2bs(b.x); v[5] = f2bs(b.y); v[6] = f2bs(b.z); v[7] = f2bs(b.w);
    *(bf16x8*)(out + i) = v;
}

// ---------------------------------------------------------------------------
// Embedding gather (fp32 residual stream)
// ---------------------------------------------------------------------------
__global__ void embed_gather(const int* __restrict__ idx,
                             const float* __restrict__ embed,
                             float* __restrict__ x) {
    int i = blockIdx.x * blockDim.x + threadIdx.x;   // 2048*192
    int m = i / 192, d4 = i % 192;
    ((float4*)x)[(size_t)m * 192 + d4] =
        ((const float4*)embed)[(size_t)idx[m] * 192 + d4];
}

// ---------------------------------------------------------------------------
// Timestep embedding
// ---------------------------------------------------------------------------
__global__ void tstep_embed(const float* __restrict__ sigma, float* __restrict__ tf) {
    int t = threadIdx.x;
    int b = t >> 7, i = t & 127;
    float freq = expf(-9.210340371976184f * (float)i / 128.f);
    float a = sigma[b] * freq;
    tf[b * 256 + i]       = cosf(a);
    tf[b * 256 + 128 + i] = sinf(a);
}

// ---------------------------------------------------------------------------
// Small-M GEMM (fp32): one wave per output element. ACT: 0 none, 2 silu
// ---------------------------------------------------------------------------
template <int ACT>
__global__ void gemm_rowvec(const float* __restrict__ A, const float* __restrict__ W,
                            const float* __restrict__ bias, float* __restrict__ C,
                            int M, int N, int K) {
    int wid  = (int)((blockIdx.x * (size_t)blockDim.x + threadIdx.x) >> 6);
    int lane = threadIdx.x & 63;
    if (wid >= M * N) return;
    int m = wid / N, n = wid % N;
    const float* a = A + (size_t)m * K;
    const float* w = W + (size_t)n * K;
    float s = 0.f;
    for (int k = lane; k < K; k += 64) s = fmaf(a[k], w[k], s);
    s = wred_sum(s);
    if (lane == 0) {
        if (bias) s += bias[n];
        if (ACT == 2) s = silu(s);
        C[wid] = s;
    }
}

// ---------------------------------------------------------------------------
// All adaLN modulations (fp32, M=2 — memory-bound on ada_w)
// ---------------------------------------------------------------------------
__global__ void ada_all(const float* __restrict__ c, const float* __restrict__ ada_w,
                        const float* __restrict__ ada_b, float* __restrict__ out) {
    const int C = 768, SIXD = 4608, B = 2;
    int wid  = (int)((blockIdx.x * (size_t)blockDim.x + threadIdx.x) >> 6);
    int lane = threadIdx.x & 63;
    if (wid >= 12 * B * SIXD) return;
    int j = wid % SIXD;
    int lb = wid / SIXD;
    int b = lb % B, l = lb / B;
    const float* a = c + (size_t)b * C;
    const float* w = ada_w + ((size_t)l * SIXD + j) * C;
    float s = 0.f;
    for (int k = lane; k < C; k += 64) s = fmaf(a[k], w[k], s);
    s = wred_sum(s);
    if (lane == 0) out[wid] = s + ada_b[l * SIXD + j];
}

// ---------------------------------------------------------------------------
// Modulated LayerNorm, fp32 in -> bf16 out (no residual fold)
// ---------------------------------------------------------------------------
__global__ __launch_bounds__(256) void ln_mod(const float* __restrict__ x,
                                              const float* __restrict__ w,
                                              const float* __restrict__ sc,
                                              const float* __restrict__ sh,
                                              int bstride,
                                              bf16* __restrict__ out) {
    int r = blockIdx.x;
    int b = r >> 10;
    const float* xr = x + (size_t)r * 768;
    int tid = threadIdx.x, lane = tid & 63, wv = tid >> 6;
    float v0 = xr[tid], v1 = xr[tid + 256], v2 = xr[tid + 512];
    __shared__ float redA[4], redB[4];
    float s = wred_sum(v0 + v1 + v2);
    if (lane == 0) redA[wv] = s;
    __syncthreads();
    float mu = (redA[0] + redA[1] + redA[2] + redA[3]) * (1.f / 768.f);
    float d0 = v0 - mu, d1 = v1 - mu, d2 = v2 - mu;
    float vs = wred_sum(d0 * d0 + d1 * d1 + d2 * d2);
    if (lane == 0) redB[wv] = vs;
    __syncthreads();
    float var  = (redB[0] + redB[1] + redB[2] + redB[3]) * (1.f / 768.f);
    float rstd = rsqrtf(var + 1e-5f);
    const float* scb = sc + (size_t)b * bstride;
    const float* shb = sh + (size_t)b * bstride;
    bf16* outr = out + (size_t)r * 768;
    outr[tid]       = __float2bfloat16(d0 * rstd * w[tid]       * (1.f + scb[tid])       + shb[tid]);
    outr[tid + 256] = __float2bfloat16(d1 * rstd * w[tid + 256] * (1.f + scb[tid + 256]) + shb[tid + 256]);
    outr[tid + 512] = __float2bfloat16(d2 * rstd * w[tid + 512] * (1.f + scb[tid + 512]) + shb[tid + 512]);
}

// ---------------------------------------------------------------------------
// Fused residual-reduce + modulated LayerNorm
// ---------------------------------------------------------------------------
template <int NPART>
__global__ __launch_bounds__(256) void ln_mod_red(float* __restrict__ x,
                                                  const float* __restrict__ part,
                                                  const float* __restrict__ bias,
                                                  const float* __restrict__ gate,
                                                  int gst,
                                                  const float* __restrict__ w,
                                                  const float* __restrict__ sc,
                                                  const float* __restrict__ sh,
                                                  int bstride,
                                                  bf16* __restrict__ out) {
    const size_t PST = (size_t)2048 * 768;
    int r = blockIdx.x;
    int b = r >> 10;
    float* xr = x + (size_t)r * 768;
    int tid = threadIdx.x, lane = tid & 63, wv = tid >> 6;

    float v[3];
    #pragma unroll
    for (int e = 0; e < 3; e++) {
        int d = tid + e * 256;
        float s0 = 0.f;
        #pragma unroll
        for (int p = 0; p < NPART; p++) s0 += part[(size_t)p * PST + (size_t)r * 768 + d];
        if (bias) s0 += bias[d];
        v[e] = xr[d] + gate[b * gst + d] * s0;
        xr[d] = v[e];
    }

    __shared__ float redA[4], redB[4];
    float s = wred_sum(v[0] + v[1] + v[2]);
    if (lane == 0) redA[wv] = s;
    __syncthreads();
    float mu = (redA[0] + redA[1] + redA[2] + redA[3]) * (1.f / 768.f);
    float d0 = v[0] - mu, d1 = v[1] - mu, d2 = v[2] - mu;
    float vs = wred_sum(d0 * d0 + d1 * d1 + d2 * d2);
    if (lane == 0) redB[wv] = vs;
    __syncthreads();
    float var  = (redB[0] + redB[1] + redB[2] + redB[3]) * (1.f / 768.f);
    float rstd = rsqrtf(var + 1e-5f);
    const float* scb = sc + (size_t)b * bstride;
    const float* shb = sh + (size_t)b * bstride;
    bf16* outr = out + (size_t)r * 768;
    outr[tid]       = __float2bfloat16(d0 * rstd * w[tid]       * (1.f + scb[tid])       + shb[tid]);
    outr[tid + 256] = __float2bfloat16(d1 * rstd * w[tid + 256] * (1.f + scb[tid + 256]) + shb[tid + 256]);
    outr[tid + 512] = __float2bfloat16(d2 * rstd * w[tid + 512] * (1.f + scb[tid + 512]) + shb[tid + 512]);
}

// ---------------------------------------------------------------------------
// bf16 MFMA GEMM (best config). 128x128 tile, 4 waves, 3-buffer LDS
// rotation, counted-vmcnt pipeline, T2 XOR-swizzle. Split-K capable.
// OMODE: 1 bf16, 3 qkv (q/k bf16 + v transposed), 4 fp32 partial.
// ---------------------------------------------------------------------------
template <int ACT, int OMODE, int SK>
__global__ __launch_bounds__(256) void gemm_mfma(const bf16* __restrict__ A,
                                                 const bf16* __restrict__ W,
                                                 const float* __restrict__ bias,
                                                 void* __restrict__ Cout,
                                                 bf16* __restrict__ vtout,
                                                 int M, int N, int K) {
    __shared__ __align__(16) bf16 SHB[6 * 128 * 32];   // 48 KB
    int tid = threadIdx.x;
    int w = tid >> 6, l = tid & 63;
    int l16 = l & 15, g = l >> 4;
    int wgid = xcd_swz(blockIdx.x, gridDim.x);
    int MT = M >> 7;
    int nt = gridDim.x / (MT * SK);
    int m0 = (wgid % MT) * 128;
    int n  = (wgid / MT) % nt;
    int s  = wgid / (MT * nt);
    int n0 = n * 128;
    int kb = K / SK;
    int k0 = s * kb;
    int wr = (w >> 1) * 64, wc = (w & 1) * 64;

    f32x4 acc[4][4];
    f32x4 zero4 = {0.f, 0.f, 0.f, 0.f};
    #pragma unroll
    for (int i = 0; i < 4; i++)
        #pragma unroll
        for (int j = 0; j < 4; j++) acc[i][j] = zero4;

    int srow = w * 32 + (l >> 2);
    int scol = ((l & 3) ^ ((l >> 3) & 3)) * 8;     // T2 pre-swizzled source
    const bf16* gA0 = A + (size_t)(m0 + srow) * K + k0 + scol;
    const bf16* gA1 = gA0 + (size_t)16 * K;
    int nr0 = n0 + srow;      if (nr0 > N - 1) nr0 = N - 1;
    int nr1 = n0 + srow + 16; if (nr1 > N - 1) nr1 = N - 1;
    const bf16* gW0 = W + (size_t)nr0 * K + k0 + scol;
    const bf16* gW1 = W + (size_t)nr1 * K + k0 + scol;
    int ldsA0 = (w * 32) * 32, ldsA1 = (w * 32 + 16) * 32;
    int sA = (g ^ ((l16 >> 1) & 3)) * 8;

    auto SAp = [&](int bufi) { return &SHB[bufi * 4096]; };
    auto SWp = [&](int bufi) { return &SHB[(3 + bufi) * 4096]; };

    int KT = kb >> 5;
    // prologue
    gload_lds16(gA0 + 0, SAp(0) + ldsA0);
    gload_lds16(gA1 + 0, SAp(0) + ldsA1);
    gload_lds16(gW0 + 0, SWp(0) + ldsA0);
    gload_lds16(gW1 + 0, SWp(0) + ldsA1);
    if (KT > 1) {
        gload_lds16(gA0 + 32, SAp(1) + ldsA0);
        gload_lds16(gA1 + 32, SAp(1) + ldsA1);
        gload_lds16(gW0 + 32, SWp(1) + ldsA0);
        gload_lds16(gW1 + 32, SWp(1) + ldsA1);
    }

    for (int k = 0; k < KT; ++k) {
        if (k == KT - 1) { WAITBAR0(); } else { WAITBAR4(); }
        if (k + 2 < KT) {
            int bufi = (k + 2) % 3, kk = (k + 2) * 32;
            gload_lds16(gA0 + kk, SAp(bufi) + ldsA0);
            gload_lds16(gA1 + kk, SAp(bufi) + ldsA1);
            gload_lds16(gW0 + kk, SWp(bufi) + ldsA0);
            gload_lds16(gW1 + kk, SWp(bufi) + ldsA1);
        }
        int cbuf = k % 3;
        const bf16* sa = SAp(cbuf);
        const bf16* sw = SWp(cbuf);
        bf16x8 af[4], bfr[4];
        #pragma unroll
        for (int mi = 0; mi < 4; mi++)
            af[mi] = *(const bf16x8*)&sa[(wr + mi * 16 + l16) * 32 + sA];
        #pragma unroll
        for (int ni = 0; ni < 4; ni++)
            bfr[ni] = *(const bf16x8*)&sw[(wc + ni * 16 + l16) * 32 + sA];
        #pragma unroll
        for (int mi = 0; mi < 4; mi++)
            #pragma unroll
            for (int ni = 0; ni < 4; ni++)
                acc[mi][ni] = __builtin_amdgcn_mfma_f32_16x16x32_bf16(
                    af[mi], bfr[ni], acc[mi][ni], 0, 0, 0);
    }

    // epilogues; C/D layout col=lane&15, row=(lane>>4)*4+reg  [m89]
    if (OMODE == 3 && n0 >= 1536) {
        #pragma unroll
        for (int ni = 0; ni < 4; ni++) {
            int cv = n0 + wc + ni * 16 + l16 - 1536;
            int h = cv >> 6, d = cv & 63;
            #pragma unroll
            for (int mi = 0; mi < 4; mi++) {
                int row = m0 + wr + mi * 16 + g * 4;
                int b = row >> 10, ss = row & 1023;
                short4 pk;
                pk.x = f2bs(acc[mi][ni][0]); pk.y = f2bs(acc[mi][ni][1]);
                pk.z = f2bs(acc[mi][ni][2]); pk.w = f2bs(acc[mi][ni][3]);
                *(short4*)&vtout[(((size_t)(b * 12 + h) * 64 + d)) * 1024 + ss] = pk;
            }
        }
        return;
    }
    float* pout = (OMODE == 4) ? (float*)Cout + (size_t)s * M * N : (float*)Cout;
    #pragma unroll
    for (int ni = 0; ni < 4; ni++) {
        int col = n0 + wc + ni * 16 + l16;
        if (col >= N) continue;
        float bv = (OMODE != 4 && bias) ? bias[col] : 0.f;
        #pragma unroll
        for (int mi = 0; mi < 4; mi++) {
            #pragma unroll
            for (int jj = 0; jj < 4; jj++) {
                int row = m0 + wr + mi * 16 + g * 4 + jj;
                float v = acc[mi][ni][jj] + bv;
                if (ACT == 1) v = gelu_tanh(v);
                if (OMODE == 1 || OMODE == 3) {
                    ((bf16*)Cout)[(size_t)row * N + col] = __float2bfloat16(v);
                } else {
                    pout[(size_t)row * N + col] = v;
                }
            }
        }
    }
}

// ---------------------------------------------------------------------------
// Vocab GEMM: 256x256 tile, 8 waves (512 thr), wave grid 2Mx4N, per-wave
// 128x64 (acc[8][4]). 2-buffer single-barrier pipeline, 66.6 KB LDS,
// 2 blocks/CU. T2 swizzle. fp32 out via LDS-bounce with 1KB contiguous runs.
// ---------------------------------------------------------------------------
__global__ __launch_bounds__(512) void gemm_vocab(const bf16* __restrict__ A,
                                                  const bf16* __restrict__ W,
                                                  const float* __restrict__ bias,
                                                  float* __restrict__ Cout,
                                                  int M, int N, int K) {
    __shared__ __align__(16) bf16 SHB[33280];   // 66.6 KB (staging 64 KB | epi 66.6 KB)
    int tid = threadIdx.x;
    int w = tid >> 6, l = tid & 63;
    int l16 = l & 15, g = l >> 4;
    int wm = w >> 2, wn = w & 3;
    int wgid = xcd_swz(blockIdx.x, gridDim.x);
    int MT = M >> 8;                  // 256-row tiles
    int m0 = (wgid % MT) * 256;
    int n0 = (wgid / MT) * 256;

    f32x4 acc[8][4];
    f32x4 zero4 = {0.f, 0.f, 0.f, 0.f};
    #pragma unroll
    for (int i = 0; i < 8; i++)
        #pragma unroll
        for (int j = 0; j < 4; j++) acc[i][j] = zero4;

    // staging: wave w covers rows [w*16, w*16+16) of each 128-row half
    int srow = w * 16 + (l >> 2);
    int scol = ((l & 3) ^ ((l >> 3) & 3)) * 8;   // T2 pre-swizzled source
    const bf16* gA0 = A + (size_t)(m0 + srow) * K + scol;
    const bf16* gA1 = gA0 + (size_t)128 * K;
    int nb0 = n0 + srow;       if (nb0 > N - 1) nb0 = N - 1;
    int nb1 = n0 + 128 + srow; if (nb1 > N - 1) nb1 = N - 1;
    const bf16* gB0 = W + (size_t)nb0 * K + scol;
    const bf16* gB1 = W + (size_t)nb1 * K + scol;
    int ldw = (w * 16) * 32;          // wave-uniform LDS base (elems)
    int sA = (g ^ ((l16 >> 1) & 3)) * 8;

    auto SAp = [&](int bufi) { return &SHB[bufi * 8192]; };
    auto SBp = [&](int bufi) { return &SHB[16384 + bufi * 8192]; };

    auto STAGE = [&](int t) {
        int bufi = t & 1, kk = t * 32;
        gload_lds16(gA0 + kk, SAp(bufi) + ldw);
        gload_lds16(gA1 + kk, SAp(bufi) + 4096 + ldw);
        gload_lds16(gB0 + kk, SBp(bufi) + ldw);
        gload_lds16(gB1 + kk, SBp(bufi) + 4096 + ldw);
    };

    int KT = K >> 5;                  // 24
    STAGE(0);

    for (int k = 0; k < KT; ++k) {
        if (k + 1 < KT) { STAGE(k + 1); WAITBAR4(); }
        else { WAITBAR0(); }
        int cbuf = k & 1;
        const bf16* sa = SAp(cbuf);
        const bf16* sb = SBp(cbuf);
        bf16x8 af[8], bfr[4];
        #pragma unroll
        for (int mi = 0; mi < 8; mi++)
            af[mi] = *(const bf16x8*)&sa[(wm * 128 + mi * 16 + l16) * 32 + sA];
        #pragma unroll
        for (int ni = 0; ni < 4; ni++)
            bfr[ni] = *(const bf16x8*)&sb[(wn * 64 + ni * 16 + l16) * 32 + sA];
        #pragma unroll
        for (int mi = 0; mi < 8; mi++)
            #pragma unroll
            for (int ni = 0; ni < 4; ni++)
                acc[mi][ni] = __builtin_amdgcn_mfma_f32_16x16x32_bf16(
                    af[mi], bfr[ni], acc[mi][ni], 0, 0, 0);
    }

    // epilogue: LDS-bounce 64 rows at a time (4 blocks); 1KB runs per wave.
    float* Lf = (float*)SHB;          // 64 x 260 f32 = 66.6 KB
    #pragma unroll
    for (int h = 0; h < 4; ++h) {
        __syncthreads();
        if (wm == (h >> 1)) {
            int mi0 = (h & 1) * 4;
            #pragma unroll
            for (int ni = 0; ni < 4; ni++) {
                int lc = wn * 64 + ni * 16 + l16;
                int colg = n0 + lc;
                float bv = (bias && colg < N) ? bias[colg] : 0.f;
                #pragma unroll
                for (int mi2 = 0; mi2 < 4; mi2++) {
                    int lr = mi2 * 16 + g * 4;
                    #pragma unroll
                    for (int jj = 0; jj < 4; jj++)
                        Lf[(lr + jj) * 260 + lc] = acc[mi0 + mi2][ni][jj] + bv;
                }
            }
        }
        __syncthreads();
        #pragma unroll
        for (int pass = 0; pass < 8; ++pass) {
            int row = pass * 8 + (tid >> 6);
            int c4  = (tid & 63) * 4;
            const float* src = &Lf[row * 260 + c4];
            float* dst = Cout + (size_t)(m0 + h * 64 + row) * N + n0 + c4;
            int col = n0 + c4;
            if (col + 3 < N) {
                *(float2*)dst       = *(const float2*)src;
                *(float2*)(dst + 2) = *(const float2*)(src + 2);
            } else {
                #pragma unroll
                for (int e = 0; e < 4; ++e)
                    if (col + e < N) dst[e] = src[e];
            }
        }
    }
}

// ---------------------------------------------------------------------------
// Flash attention, bf16 MFMA. 3-buffer counted-vmcnt KV pipeline.
// 32-row q-tiles, 2 waves (128 thr), 768 blocks = 3.0/CU exact.
// ---------------------------------------------------------------------------
__global__ __launch_bounds__(128) void attn_mfma(const bf16* __restrict__ qkv,
                                                 const bf16* __restrict__ vt,
                                                 bf16* __restrict__ ao) {
    const int S = 1024, C3 = 2304;
    int wgid = xcd_swz(blockIdx.x, gridDim.x);
    int bh = wgid >> 5, b = bh / 12, h = bh % 12;
    int q0 = (wgid & 31) * 32;
    int tid = threadIdx.x, w = tid >> 6, l = tid & 63;
    int l16 = l & 15, g = l >> 4;

    __shared__ __align__(16) bf16 Ks[3][64 * 64];
    __shared__ __align__(16) bf16 Vs[3][64 * 64];   // [d][key], swizzled rows
    __shared__ __align__(16) bf16 Ps[2][16 * 72];   // per-wave private

    const size_t qbase = ((size_t)(b * S + q0 + w * 16 + l16)) * C3 + h * 64;
    bf16x8 qf[2];
    qf[0] = *(const bf16x8*)&qkv[qbase + g * 8];
    qf[1] = *(const bf16x8*)&qkv[qbase + 32 + g * 8];

    f32x4 o_acc[4];
    f32x4 zero4 = {0.f, 0.f, 0.f, 0.f};
    #pragma unroll
    for (int ni = 0; ni < 4; ni++) o_acc[ni] = zero4;
    float mrow[4] = {-1e30f, -1e30f, -1e30f, -1e30f};
    float lrow[4] = {0.f, 0.f, 0.f, 0.f};
    const float cscale = 0.125f * 1.44269504088896f;   // log2(e)/sqrt(dh)

    int sr0 = w * 32 + (l >> 3);          // +8 per issue
    int cb  = (l & 7) * 16;
    int sc0 = (cb ^ ((sr0 & 7) << 4)) >> 1;
    const bf16* gk0 = qkv + ((size_t)(b * S) + sr0) * C3 + 768 + h * 64 + sc0;
    const bf16* gv0 = vt + ((size_t)bh * 64 + sr0) * 1024 + sc0;
    int ldk0 = (w * 32) * 64;

    auto STAGEKV = [&](int t, int bufi) {
        #pragma unroll
        for (int e = 0; e < 4; e++) {
            gload_lds16(gk0 + (size_t)(t * 64 + e * 8) * C3, &Ks[bufi][ldk0 + e * 8 * 64]);
            gload_lds16(gv0 + t * 64 + (size_t)e * 8 * 1024, &Vs[bufi][ldk0 + e * 8 * 64]);
        }
    };

    STAGEKV(0, 0);
    STAGEKV(1, 1);

    for (int it = 0; it < 16; ++it) {
        if (it == 15) { WAITBAR0(); } else { WAITBAR8(); }
        if (it + 2 < 16) STAGEKV(it + 2, (it + 2) % 3);
        int cur = it % 3;

        f32x4 sfrag[4];
        #pragma unroll
        for (int kf = 0; kf < 4; kf++) {
            sfrag[kf] = zero4;
            int key = kf * 16 + l16;
            #pragma unroll
            for (int kc = 0; kc < 2; kc++) {
                int byteoff = key * 128 + (((kc * 32 + g * 8) * 2) ^ ((key & 7) << 4));
                bf16x8 kb = *(const bf16x8*)((const char*)Ks[cur] + byteoff);
                sfrag[kf] = __builtin_amdgcn_mfma_f32_16x16x32_bf16(qf[kc], kb, sfrag[kf], 0, 0, 0);
            }
        }

        float pv[4][4];
        #pragma unroll
        for (int j = 0; j < 4; j++) {
            float t0 = sfrag[0][j] * cscale, t1 = sfrag[1][j] * cscale;
            float t2 = sfrag[2][j] * cscale, t3 = sfrag[3][j] * cscale;
            float mx = fmaxf(fmaxf(t0, t1), fmaxf(t2, t3));
            mx = red16_max(mx);
            float mnew = fmaxf(mrow[j], mx);
            float r = exp2f(mrow[j] - mnew);
            mrow[j] = mnew;
            float p0 = exp2f(t0 - mnew), p1 = exp2f(t1 - mnew);
            float p2 = exp2f(t2 - mnew), p3 = exp2f(t3 - mnew);
            pv[0][j] = p0; pv[1][j] = p1; pv[2][j] = p2; pv[3][j] = p3;
            float ps = red16_sum(p0 + p1 + p2 + p3);
            lrow[j] = lrow[j] * r + ps;
            #pragma unroll
            for (int ni = 0; ni < 4; ni++) o_acc[ni][j] *= r;
        }

        // P: C-layout -> A-layout via per-wave LDS (no barrier: wave-private)
        #pragma unroll
        for (int kf = 0; kf < 4; kf++)
            #pragma unroll
            for (int j = 0; j < 4; j++)
                Ps[w][(g * 4 + j) * 72 + kf * 16 + l16] = __float2bfloat16(pv[kf][j]);

        #pragma unroll
        for (int kc = 0; kc < 2; kc++) {
            bf16x8 pa = *(const bf16x8*)&Ps[w][l16 * 72 + kc * 32 + g * 8];
            #pragma unroll
            for (int ni = 0; ni < 4; ni++) {
                int d = ni * 16 + l16;
                int byteoff = d * 128 + (((kc * 32 + g * 8) * 2) ^ ((d & 7) << 4));
                bf16x8 vb = *(const bf16x8*)((const char*)Vs[cur] + byteoff);
                o_acc[ni] = __builtin_amdgcn_mfma_f32_16x16x32_bf16(pa, vb, o_acc[ni], 0, 0, 0);
            }
        }
    }

    float linv[4];
    #pragma unroll
    for (int j = 0; j < 4; j++) linv[j] = 1.f / lrow[j];
    #pragma unroll
    for (int ni = 0; ni < 4; ni++) {
        #pragma unroll
        for (int jj = 0; jj < 4; jj++) {
            int row = q0 + w * 16 + g * 4 + jj;
            ao[((size_t)(b * S + row)) * 768 + h * 64 + ni * 16 + l16] =
                __float2bfloat16(o_acc[ni][jj] * linv[jj]);
        }
    }
}

// ---------------------------------------------------------------------------
// Host orchestration
// ---------------------------------------------------------------------------
extern "C" void kernel_launch(void* const* d_in, const int* in_sizes, int n_in,
                              void* d_out, int out_size, void* d_ws, size_t ws_size,
                              hipStream_t stream) {
    const int B = 2, S = 1024, D = 768, L = 12, V = 50258, C = 768, F = 256, MLP = 3072;
    const int M = B * S;

    const int*   indices = (const int*)d_in[0];
    const float* sigma   = (const float*)d_in[1];
    const float* embed   = (const float*)d_in[2];
    const float* t_w1    = (const float*)d_in[3];
    const float* t_b1    = (const float*)d_in[4];
    const float* t_w2    = (const float*)d_in[5];
    const float* t_b2    = (const float*)d_in[6];
    const float* norm1_w = (const float*)d_in[7];
    const float* qkv_w   = (const float*)d_in[8];
    const float* out_w   = (const float*)d_in[9];
    const float* norm2_w = (const float*)d_in[10];
    const float* mlp_w1  = (const float*)d_in[11];
    const float* mlp_b1  = (const float*)d_in[12];
    const float* mlp_w2  = (const float*)d_in[13];
    const float* mlp_b2  = (const float*)d_in[14];
    const float* ada_w   = (const float*)d_in[15];
    const float* ada_b   = (const float*)d_in[16];
    const float* normf_w = (const float*)d_in[17];
    const float* lin_w   = (const float*)d_in[18];
    const float* lin_b   = (const float*)d_in[19];
    const float* adaf_w  = (const float*)d_in[20];
    const float* adaf_b  = (const float*)d_in[21];

    char* p = (char*)d_ws;
    auto alloc = [&](size_t bytes) { char* r = p; p += (bytes + 255) & ~(size_t)255; return r; };

    float* x     = (float*)alloc((size_t)M * D * 4);
    bf16*  xm    = (bf16*) alloc((size_t)M * D * 2);
    bf16*  qkvb  = (bf16*) alloc((size_t)M * 3 * D * 2);
    bf16*  aob   = (bf16*) alloc((size_t)M * D * 2);
    bf16*  hbb   = (bf16*) alloc((size_t)M * MLP * 2);
    bf16*  vtb   = (bf16*) alloc((size_t)24 * 64 * 1024 * 2);
    float* partb = (float*)alloc((size_t)4 * M * D * 4);   // split-K partials
    bf16*  linb  = (bf16*) alloc((size_t)V * D * 2);
    float* tf    = (float*)alloc((size_t)B * F * 4);
    float* h1    = (float*)alloc((size_t)B * C * 4);
    float* cb    = (float*)alloc((size_t)B * C * 4);
    float* ada   = (float*)alloc((size_t)L * B * 6 * D * 4);
    float* adaf  = (float*)alloc((size_t)B * 2 * D * 4);

    const size_t n_qkvw = (size_t)L * 2304 * 768;
    const size_t n_outw = (size_t)L * 768 * 768;
    const size_t n_w1   = (size_t)L * 3072 * 768;
    const size_t n_w2   = (size_t)L * 768 * 3072;
    const size_t per_layer = (size_t)(2304 + 768 + 3072 + 3072) * 768;
    size_t used = (size_t)(p - (char*)d_ws);
    bool all_w = (ws_size - used) >= ((n_qkvw + n_outw + n_w1 + n_w2) * 2 + 1024);

    bf16 *wqkv, *wout, *ww1, *ww2;
    if (all_w) {
        wqkv = (bf16*)alloc(n_qkvw * 2);
        wout = (bf16*)alloc(n_outw * 2);
        ww1  = (bf16*)alloc(n_w1 * 2);
        ww2  = (bf16*)alloc(n_w2 * 2);
    } else {
        bf16* wl = (bf16*)alloc(per_layer * 2);
        wqkv = wl;
        wout = wqkv + (size_t)2304 * 768;
        ww1  = wout + (size_t)768 * 768;
        ww2  = ww1 + (size_t)3072 * 768;
    }

    auto cgrid = [](long n) { return (unsigned)((n / 8 + 255) / 256); };
    dim3 blk(256);

    // prologue
    embed_gather<<<(M * 192) / 256, blk, 0, stream>>>(indices, embed, x);
    tstep_embed<<<1, blk, 0, stream>>>(sigma, tf);
    gemm_rowvec<2><<<(B * C * 64) / 256, blk, 0, stream>>>(tf, t_w1, t_b1, h1, B, C, F);
    gemm_rowvec<2><<<(B * C * 64) / 256, blk, 0, stream>>>(h1, t_w2, t_b2, cb, B, C, C);
    ada_all<<<(L * B * 6 * D * 64) / 256, blk, 0, stream>>>(cb, ada_w, ada_b, ada);
    gemm_rowvec<0><<<(B * 2 * D * 64) / 256, blk, 0, stream>>>(cb, adaf_w, adaf_b, adaf, B, 2 * D, C);
    cvt_bf16<<<cgrid((long)V * D), blk, 0, stream>>>(lin_w, linb, (long)V * D);
    if (all_w) {
        cvt_bf16<<<cgrid((long)n_qkvw), blk, 0, stream>>>(qkv_w, wqkv, (long)n_qkvw);
        cvt_bf16<<<cgrid((long)n_outw), blk, 0, stream>>>(out_w, wout, (long)n_outw);
        cvt_bf16<<<cgrid((long)n_w1),   blk, 0, stream>>>(mlp_w1, ww1, (long)n_w1);
        cvt_bf16<<<cgrid((long)n_w2),   blk, 0, stream>>>(mlp_w2, ww2, (long)n_w2);
    }

    const int MT = M / 128;
    for (int l = 0; l < L; l++) {
        const float* adaL = ada + (size_t)l * B * 6 * D;
        bf16 *wq, *wo, *w1, *w2;
        if (all_w) {
            wq = wqkv + (size_t)l * 2304 * 768;
            wo = wout + (size_t)l * 768 * 768;
            w1 = ww1 + (size_t)l * 3072 * 768;
            w2 = ww2 + (size_t)l * 768 * 3072;
        } else {
            wq = wqkv; wo = wout; w1 = ww1; w2 = ww2;
            cvt_bf16<<<cgrid((long)2304 * 768), blk, 0, stream>>>(qkv_w + (size_t)l * 2304 * 768, wq, (long)2304 * 768);
            cvt_bf16<<<cgrid((long)768 * 768),  blk, 0, stream>>>(out_w + (size_t)l * 768 * 768,  wo, (long)768 * 768);
            cvt_bf16<<<cgrid((long)3072 * 768), blk, 0, stream>>>(mlp_w1 + (size_t)l * 3072 * 768, w1, (long)3072 * 768);
            cvt_bf16<<<cgrid((long)768 * 3072), blk, 0, stream>>>(mlp_w2 + (size_t)l * 768 * 3072, w2, (long)768 * 3072);
        }

        // norm1: layer 0 plain; layers 1.. fold previous layer's mlp2 partials
        if (l == 0) {
            ln_mod<<<M, blk, 0, stream>>>(x, norm1_w, adaL + D, adaL, 6 * D, xm);
        } else {
            const float* adaP = ada + (size_t)(l - 1) * B * 6 * D;
            ln_mod_red<4><<<M, blk, 0, stream>>>(
                x, partb, mlp_b2 + (size_t)(l - 1) * D, adaP + 5 * D, 6 * D,
                norm1_w + (size_t)l * D, adaL + D, adaL, 6 * D, xm);
        }

        // qkv GEMM: q/k -> qkvb, v -> vtb (transposed) fused
        gemm_mfma<0, 3, 1><<<MT * (2304 / 128), blk, 0, stream>>>(
            xm, wq, nullptr, qkvb, vtb, M, 2304, 768);
        attn_mfma<<<768, dim3(128), 0, stream>>>(qkvb, vtb, aob);
        // out-proj: split-K x4 -> partials (384 blocks = 1.5/CU, was 192)
        gemm_mfma<0, 4, 4><<<MT * (768 / 128) * 4, blk, 0, stream>>>(
            aob, wo, nullptr, partb, nullptr, M, 768, 768);
        // norm2 folds attn residual (4 partials)
        ln_mod_red<4><<<M, blk, 0, stream>>>(
            x, partb, nullptr, adaL + 2 * D, 6 * D,
            norm2_w + (size_t)l * D, adaL + 4 * D, adaL + 3 * D, 6 * D, xm);

        gemm_mfma<1, 1, 1><<<MT * (3072 / 128), blk, 0, stream>>>(
            xm, w1, mlp_b1 + (size_t)l * MLP, hbb, nullptr, M, 3072, 768);
        // mlp2: split-K x4 -> partials (folded by next norm1 / final norm)
        gemm_mfma<0, 4, 4><<<MT * (768 / 128) * 4, blk, 0, stream>>>(
            hbb, w2, nullptr, partb, nullptr, M, 768, 3072);
    }

    // final: fold last mlp2 residual + normf
    {
        const float* adaP = ada + (size_t)(L - 1) * B * 6 * D;
        ln_mod_red<4><<<M, blk, 0, stream>>>(
            x, partb, mlp_b2 + (size_t)(L - 1) * D, adaP + 5 * D, 6 * D,
            normf_w, adaf + D, adaf, 2 * D, xm);
    }
    // vocab: 256^2 8-wave kernel, 2-buffer pipeline, 2 blocks/CU
    gemm_vocab<<<(M / 256) * ((V + 255) / 256), dim3(512), 0, stream>>>(
        xm, linb, lin_b, (float*)d_out, M, V, 768);
}

// Round 20
// 2057.658 us; speedup vs baseline: 1.0099x; 1.0099x over previous
//
#include <hip/hip_runtime.h>
#include <hip/hip_bf16.h>
#include <math.h>
#include <stdint.h>

typedef __hip_bfloat16 bf16;
typedef __attribute__((ext_vector_type(8))) short bf16x8;   // 8 bf16 = 4 VGPR
typedef __attribute__((ext_vector_type(4))) float f32x4;

#define DEV_INLINE __device__ __forceinline__

DEV_INLINE float wred_sum(float v) {
    #pragma unroll
    for (int o = 32; o > 0; o >>= 1) v += __shfl_xor(v, o);
    return v;
}
DEV_INLINE float red16_max(float v) {
    v = fmaxf(v, __shfl_xor(v, 1)); v = fmaxf(v, __shfl_xor(v, 2));
    v = fmaxf(v, __shfl_xor(v, 4)); v = fmaxf(v, __shfl_xor(v, 8));
    return v;
}
DEV_INLINE float red16_sum(float v) {
    v += __shfl_xor(v, 1); v += __shfl_xor(v, 2);
    v += __shfl_xor(v, 4); v += __shfl_xor(v, 8);
    return v;
}
DEV_INLINE float gelu_tanh(float v) {
    float t = tanhf(0.7978845608028654f * (v + 0.044715f * v * v * v));
    return 0.5f * v * (1.f + t);
}
DEV_INLINE float silu(float v) { return v / (1.f + expf(-v)); }
DEV_INLINE short f2bs(float f) { bf16 h = __float2bfloat16(f); short s; __builtin_memcpy(&s, &h, 2); return s; }

typedef const __attribute__((address_space(1))) uint32_t* gptr_t;
typedef __attribute__((address_space(3))) uint32_t* lptr_t;

DEV_INLINE void gload_lds16(const bf16* gp, bf16* lp) {
    __builtin_amdgcn_global_load_lds((gptr_t)gp, (lptr_t)lp, 16, 0, 0);
}

// counted-vmcnt barrier: wait own loads down to N outstanding, then s_barrier.
#define WAITBAR8() asm volatile("s_waitcnt vmcnt(8)\ns_barrier" ::: "memory")
#define WAITBAR4() asm volatile("s_waitcnt vmcnt(4)\ns_barrier" ::: "memory")
#define WAITBAR0() asm volatile("s_waitcnt vmcnt(0)\ns_barrier" ::: "memory")

// bijective XCD-chunk swizzle (m204)
DEV_INLINE int xcd_swz(int wg, int nwg) {
    int q = nwg >> 3, r = nwg & 7;
    int xcd = wg & 7, pos = wg >> 3;
    return (xcd < r ? xcd * (q + 1) : r * (q + 1) + (xcd - r) * q) + pos;
}

// ---------------------------------------------------------------------------
// fp32 -> bf16 conversion, 8 elems/thread, n multiple of 8
// ---------------------------------------------------------------------------
__global__ void cvt_bf16(const float* __restrict__ in, bf16* __restrict__ out, long n) {
    long i = ((long)blockIdx.x * blockDim.x + threadIdx.x) * 8;
    if (i >= n) return;
    float4 a = *(const float4*)(in + i);
    float4 b = *(const float4*)(in + i + 4);
    bf16x8 v;
    v[0] = f2bs(a.x); v[1] = f2bs(a.y); v[2] = f2bs(a.z); v[3] = f2bs(a.w);
    v[4] = f2bs(b.x); v[5] = f2bs(b.y); v[6] = f2bs(b.z); v[7] = f2bs(b.w);
    *(bf16x8*)(out + i) = v;
}

// ---------------------------------------------------------------------------
// Embedding gather (fp32 residual stream)
// ---------------------------------------------------------------------------
__global__ void embed_gather(const int* __restrict__ idx,
                             const float* __restrict__ embed,
                             float* __restrict__ x) {
    int i = blockIdx.x * blockDim.x + threadIdx.x;   // 2048*192
    int m = i / 192, d4 = i % 192;
    ((float4*)x)[(size_t)m * 192 + d4] =
        ((const float4*)embed)[(size_t)idx[m] * 192 + d4];
}

// ---------------------------------------------------------------------------
// Timestep embedding
// ---------------------------------------------------------------------------
__global__ void tstep_embed(const float* __restrict__ sigma, float* __restrict__ tf) {
    int t = threadIdx.x;
    int b = t >> 7, i = t & 127;
    float freq = expf(-9.210340371976184f * (float)i / 128.f);
    float a = sigma[b] * freq;
    tf[b * 256 + i]       = cosf(a);
    tf[b * 256 + 128 + i] = sinf(a);
}

// ---------------------------------------------------------------------------
// Small-M GEMM (fp32): one wave per output element. ACT: 0 none, 2 silu
// ---------------------------------------------------------------------------
template <int ACT>
__global__ void gemm_rowvec(const float* __restrict__ A, const float* __restrict__ W,
                            const float* __restrict__ bias, float* __restrict__ C,
                            int M, int N, int K) {
    int wid  = (int)((blockIdx.x * (size_t)blockDim.x + threadIdx.x) >> 6);
    int lane = threadIdx.x & 63;
    if (wid >= M * N) return;
    int m = wid / N, n = wid % N;
    const float* a = A + (size_t)m * K;
    const float* w = W + (size_t)n * K;
    float s = 0.f;
    for (int k = lane; k < K; k += 64) s = fmaf(a[k], w[k], s);
    s = wred_sum(s);
    if (lane == 0) {
        if (bias) s += bias[n];
        if (ACT == 2) s = silu(s);
        C[wid] = s;
    }
}

// ---------------------------------------------------------------------------
// All adaLN modulations (fp32, M=2 — memory-bound on ada_w)
// ---------------------------------------------------------------------------
__global__ void ada_all(const float* __restrict__ c, const float* __restrict__ ada_w,
                        const float* __restrict__ ada_b, float* __restrict__ out) {
    const int C = 768, SIXD = 4608, B = 2;
    int wid  = (int)((blockIdx.x * (size_t)blockDim.x + threadIdx.x) >> 6);
    int lane = threadIdx.x & 63;
    if (wid >= 12 * B * SIXD) return;
    int j = wid % SIXD;
    int lb = wid / SIXD;
    int b = lb % B, l = lb / B;
    const float* a = c + (size_t)b * C;
    const float* w = ada_w + ((size_t)l * SIXD + j) * C;
    float s = 0.f;
    for (int k = lane; k < C; k += 64) s = fmaf(a[k], w[k], s);
    s = wred_sum(s);
    if (lane == 0) out[wid] = s + ada_b[l * SIXD + j];
}

// ---------------------------------------------------------------------------
// Modulated LayerNorm, fp32 in -> bf16 out (no residual fold)
// ---------------------------------------------------------------------------
__global__ __launch_bounds__(256) void ln_mod(const float* __restrict__ x,
                                              const float* __restrict__ w,
                                              const float* __restrict__ sc,
                                              const float* __restrict__ sh,
                                              int bstride,
                                              bf16* __restrict__ out) {
    int r = blockIdx.x;
    int b = r >> 10;
    const float* xr = x + (size_t)r * 768;
    int tid = threadIdx.x, lane = tid & 63, wv = tid >> 6;
    float v0 = xr[tid], v1 = xr[tid + 256], v2 = xr[tid + 512];
    __shared__ float redA[4], redB[4];
    float s = wred_sum(v0 + v1 + v2);
    if (lane == 0) redA[wv] = s;
    __syncthreads();
    float mu = (redA[0] + redA[1] + redA[2] + redA[3]) * (1.f / 768.f);
    float d0 = v0 - mu, d1 = v1 - mu, d2 = v2 - mu;
    float vs = wred_sum(d0 * d0 + d1 * d1 + d2 * d2);
    if (lane == 0) redB[wv] = vs;
    __syncthreads();
    float var  = (redB[0] + redB[1] + redB[2] + redB[3]) * (1.f / 768.f);
    float rstd = rsqrtf(var + 1e-5f);
    const float* scb = sc + (size_t)b * bstride;
    const float* shb = sh + (size_t)b * bstride;
    bf16* outr = out + (size_t)r * 768;
    outr[tid]       = __float2bfloat16(d0 * rstd * w[tid]       * (1.f + scb[tid])       + shb[tid]);
    outr[tid + 256] = __float2bfloat16(d1 * rstd * w[tid + 256] * (1.f + scb[tid + 256]) + shb[tid + 256]);
    outr[tid + 512] = __float2bfloat16(d2 * rstd * w[tid + 512] * (1.f + scb[tid + 512]) + shb[tid + 512]);
}

// ---------------------------------------------------------------------------
// Fused residual-reduce + modulated LayerNorm
// ---------------------------------------------------------------------------
template <int NPART>
__global__ __launch_bounds__(256) void ln_mod_red(float* __restrict__ x,
                                                  const float* __restrict__ part,
                                                  const float* __restrict__ bias,
                                                  const float* __restrict__ gate,
                                                  int gst,
                                                  const float* __restrict__ w,
                                                  const float* __restrict__ sc,
                                                  const float* __restrict__ sh,
                                                  int bstride,
                                                  bf16* __restrict__ out) {
    const size_t PST = (size_t)2048 * 768;
    int r = blockIdx.x;
    int b = r >> 10;
    float* xr = x + (size_t)r * 768;
    int tid = threadIdx.x, lane = tid & 63, wv = tid >> 6;

    float v[3];
    #pragma unroll
    for (int e = 0; e < 3; e++) {
        int d = tid + e * 256;
        float s0 = 0.f;
        #pragma unroll
        for (int p = 0; p < NPART; p++) s0 += part[(size_t)p * PST + (size_t)r * 768 + d];
        if (bias) s0 += bias[d];
        v[e] = xr[d] + gate[b * gst + d] * s0;
        xr[d] = v[e];
    }

    __shared__ float redA[4], redB[4];
    float s = wred_sum(v[0] + v[1] + v[2]);
    if (lane == 0) redA[wv] = s;
    __syncthreads();
    float mu = (redA[0] + redA[1] + redA[2] + redA[3]) * (1.f / 768.f);
    float d0 = v[0] - mu, d1 = v[1] - mu, d2 = v[2] - mu;
    float vs = wred_sum(d0 * d0 + d1 * d1 + d2 * d2);
    if (lane == 0) redB[wv] = vs;
    __syncthreads();
    float var  = (redB[0] + redB[1] + redB[2] + redB[3]) * (1.f / 768.f);
    float rstd = rsqrtf(var + 1e-5f);
    const float* scb = sc + (size_t)b * bstride;
    const float* shb = sh + (size_t)b * bstride;
    bf16* outr = out + (size_t)r * 768;
    outr[tid]       = __float2bfloat16(d0 * rstd * w[tid]       * (1.f + scb[tid])       + shb[tid]);
    outr[tid + 256] = __float2bfloat16(d1 * rstd * w[tid + 256] * (1.f + scb[tid + 256]) + shb[tid + 256]);
    outr[tid + 512] = __float2bfloat16(d2 * rstd * w[tid + 512] * (1.f + scb[tid + 512]) + shb[tid + 512]);
}

// ---------------------------------------------------------------------------
// bf16 MFMA GEMM (best config). 128x128 tile, 4 waves, 3-buffer LDS
// rotation, counted-vmcnt pipeline, T2 XOR-swizzle. Split-K capable.
// OMODE: 1 bf16, 3 qkv (q/k bf16 + v transposed), 4 fp32 partial.
// ---------------------------------------------------------------------------
template <int ACT, int OMODE, int SK>
__global__ __launch_bounds__(256) void gemm_mfma(const bf16* __restrict__ A,
                                                 const bf16* __restrict__ W,
                                                 const float* __restrict__ bias,
                                                 void* __restrict__ Cout,
                                                 bf16* __restrict__ vtout,
                                                 int M, int N, int K) {
    __shared__ __align__(16) bf16 SHB[6 * 128 * 32];   // 48 KB
    int tid = threadIdx.x;
    int w = tid >> 6, l = tid & 63;
    int l16 = l & 15, g = l >> 4;
    int wgid = xcd_swz(blockIdx.x, gridDim.x);
    int MT = M >> 7;
    int nt = gridDim.x / (MT * SK);
    int m0 = (wgid % MT) * 128;
    int n  = (wgid / MT) % nt;
    int s  = wgid / (MT * nt);
    int n0 = n * 128;
    int kb = K / SK;
    int k0 = s * kb;
    int wr = (w >> 1) * 64, wc = (w & 1) * 64;

    f32x4 acc[4][4];
    f32x4 zero4 = {0.f, 0.f, 0.f, 0.f};
    #pragma unroll
    for (int i = 0; i < 4; i++)
        #pragma unroll
        for (int j = 0; j < 4; j++) acc[i][j] = zero4;

    int srow = w * 32 + (l >> 2);
    int scol = ((l & 3) ^ ((l >> 3) & 3)) * 8;     // T2 pre-swizzled source
    const bf16* gA0 = A + (size_t)(m0 + srow) * K + k0 + scol;
    const bf16* gA1 = gA0 + (size_t)16 * K;
    int nr0 = n0 + srow;      if (nr0 > N - 1) nr0 = N - 1;
    int nr1 = n0 + srow + 16; if (nr1 > N - 1) nr1 = N - 1;
    const bf16* gW0 = W + (size_t)nr0 * K + k0 + scol;
    const bf16* gW1 = W + (size_t)nr1 * K + k0 + scol;
    int ldsA0 = (w * 32) * 32, ldsA1 = (w * 32 + 16) * 32;
    int sA = (g ^ ((l16 >> 1) & 3)) * 8;

    auto SAp = [&](int bufi) { return &SHB[bufi * 4096]; };
    auto SWp = [&](int bufi) { return &SHB[(3 + bufi) * 4096]; };

    int KT = kb >> 5;
    // prologue
    gload_lds16(gA0 + 0, SAp(0) + ldsA0);
    gload_lds16(gA1 + 0, SAp(0) + ldsA1);
    gload_lds16(gW0 + 0, SWp(0) + ldsA0);
    gload_lds16(gW1 + 0, SWp(0) + ldsA1);
    if (KT > 1) {
        gload_lds16(gA0 + 32, SAp(1) + ldsA0);
        gload_lds16(gA1 + 32, SAp(1) + ldsA1);
        gload_lds16(gW0 + 32, SWp(1) + ldsA0);
        gload_lds16(gW1 + 32, SWp(1) + ldsA1);
    }

    for (int k = 0; k < KT; ++k) {
        if (k == KT - 1) { WAITBAR0(); } else { WAITBAR4(); }
        if (k + 2 < KT) {
            int bufi = (k + 2) % 3, kk = (k + 2) * 32;
            gload_lds16(gA0 + kk, SAp(bufi) + ldsA0);
            gload_lds16(gA1 + kk, SAp(bufi) + ldsA1);
            gload_lds16(gW0 + kk, SWp(bufi) + ldsA0);
            gload_lds16(gW1 + kk, SWp(bufi) + ldsA1);
        }
        int cbuf = k % 3;
        const bf16* sa = SAp(cbuf);
        const bf16* sw = SWp(cbuf);
        bf16x8 af[4], bfr[4];
        #pragma unroll
        for (int mi = 0; mi < 4; mi++)
            af[mi] = *(const bf16x8*)&sa[(wr + mi * 16 + l16) * 32 + sA];
        #pragma unroll
        for (int ni = 0; ni < 4; ni++)
            bfr[ni] = *(const bf16x8*)&sw[(wc + ni * 16 + l16) * 32 + sA];
        #pragma unroll
        for (int mi = 0; mi < 4; mi++)
            #pragma unroll
            for (int ni = 0; ni < 4; ni++)
                acc[mi][ni] = __builtin_amdgcn_mfma_f32_16x16x32_bf16(
                    af[mi], bfr[ni], acc[mi][ni], 0, 0, 0);
    }

    // epilogues; C/D layout col=lane&15, row=(lane>>4)*4+reg  [m89]
    if (OMODE == 3 && n0 >= 1536) {
        #pragma unroll
        for (int ni = 0; ni < 4; ni++) {
            int cv = n0 + wc + ni * 16 + l16 - 1536;
            int h = cv >> 6, d = cv & 63;
            #pragma unroll
            for (int mi = 0; mi < 4; mi++) {
                int row = m0 + wr + mi * 16 + g * 4;
                int b = row >> 10, ss = row & 1023;
                short4 pk;
                pk.x = f2bs(acc[mi][ni][0]); pk.y = f2bs(acc[mi][ni][1]);
                pk.z = f2bs(acc[mi][ni][2]); pk.w = f2bs(acc[mi][ni][3]);
                *(short4*)&vtout[(((size_t)(b * 12 + h) * 64 + d)) * 1024 + ss] = pk;
            }
        }
        return;
    }
    float* pout = (OMODE == 4) ? (float*)Cout + (size_t)s * M * N : (float*)Cout;
    #pragma unroll
    for (int ni = 0; ni < 4; ni++) {
        int col = n0 + wc + ni * 16 + l16;
        if (col >= N) continue;
        float bv = (OMODE != 4 && bias) ? bias[col] : 0.f;
        #pragma unroll
        for (int mi = 0; mi < 4; mi++) {
            #pragma unroll
            for (int jj = 0; jj < 4; jj++) {
                int row = m0 + wr + mi * 16 + g * 4 + jj;
                float v = acc[mi][ni][jj] + bv;
                if (ACT == 1) v = gelu_tanh(v);
                if (OMODE == 1 || OMODE == 3) {
                    ((bf16*)Cout)[(size_t)row * N + col] = __float2bfloat16(v);
                } else {
                    pout[(size_t)row * N + col] = v;
                }
            }
        }
    }
}

// ---------------------------------------------------------------------------
// Vocab GEMM: 256x256 tile, 8 waves (512 thr), wave grid 2Mx4N, per-wave
// 128x64 (acc[8][4]). 2-buffer single-barrier pipeline, 66.6 KB LDS,
// 2 blocks/CU. T2 swizzle. fp32 out via LDS-bounce with 1KB contiguous runs.
// ---------------------------------------------------------------------------
__global__ __launch_bounds__(512) void gemm_vocab(const bf16* __restrict__ A,
                                                  const bf16* __restrict__ W,
                                                  const float* __restrict__ bias,
                                                  float* __restrict__ Cout,
                                                  int M, int N, int K) {
    __shared__ __align__(16) bf16 SHB[33280];   // 66.6 KB (staging 64 KB | epi 66.6 KB)
    int tid = threadIdx.x;
    int w = tid >> 6, l = tid & 63;
    int l16 = l & 15, g = l >> 4;
    int wm = w >> 2, wn = w & 3;
    int wgid = xcd_swz(blockIdx.x, gridDim.x);
    int MT = M >> 8;                  // 256-row tiles
    int m0 = (wgid % MT) * 256;
    int n0 = (wgid / MT) * 256;

    f32x4 acc[8][4];
    f32x4 zero4 = {0.f, 0.f, 0.f, 0.f};
    #pragma unroll
    for (int i = 0; i < 8; i++)
        #pragma unroll
        for (int j = 0; j < 4; j++) acc[i][j] = zero4;

    // staging: wave w covers rows [w*16, w*16+16) of each 128-row half
    int srow = w * 16 + (l >> 2);
    int scol = ((l & 3) ^ ((l >> 3) & 3)) * 8;   // T2 pre-swizzled source
    const bf16* gA0 = A + (size_t)(m0 + srow) * K + scol;
    const bf16* gA1 = gA0 + (size_t)128 * K;
    int nb0 = n0 + srow;       if (nb0 > N - 1) nb0 = N - 1;
    int nb1 = n0 + 128 + srow; if (nb1 > N - 1) nb1 = N - 1;
    const bf16* gB0 = W + (size_t)nb0 * K + scol;
    const bf16* gB1 = W + (size_t)nb1 * K + scol;
    int ldw = (w * 16) * 32;          // wave-uniform LDS base (elems)
    int sA = (g ^ ((l16 >> 1) & 3)) * 8;

    auto SAp = [&](int bufi) { return &SHB[bufi * 8192]; };
    auto SBp = [&](int bufi) { return &SHB[16384 + bufi * 8192]; };

    auto STAGE = [&](int t) {
        int bufi = t & 1, kk = t * 32;
        gload_lds16(gA0 + kk, SAp(bufi) + ldw);
        gload_lds16(gA1 + kk, SAp(bufi) + 4096 + ldw);
        gload_lds16(gB0 + kk, SBp(bufi) + ldw);
        gload_lds16(gB1 + kk, SBp(bufi) + 4096 + ldw);
    };

    int KT = K >> 5;                  // 24
    STAGE(0);

    for (int k = 0; k < KT; ++k) {
        if (k + 1 < KT) { STAGE(k + 1); WAITBAR4(); }
        else { WAITBAR0(); }
        int cbuf = k & 1;
        const bf16* sa = SAp(cbuf);
        const bf16* sb = SBp(cbuf);
        bf16x8 af[8], bfr[4];
        #pragma unroll
        for (int mi = 0; mi < 8; mi++)
            af[mi] = *(const bf16x8*)&sa[(wm * 128 + mi * 16 + l16) * 32 + sA];
        #pragma unroll
        for (int ni = 0; ni < 4; ni++)
            bfr[ni] = *(const bf16x8*)&sb[(wn * 64 + ni * 16 + l16) * 32 + sA];
        #pragma unroll
        for (int mi = 0; mi < 8; mi++)
            #pragma unroll
            for (int ni = 0; ni < 4; ni++)
                acc[mi][ni] = __builtin_amdgcn_mfma_f32_16x16x32_bf16(
                    af[mi], bfr[ni], acc[mi][ni], 0, 0, 0);
    }

    // epilogue: LDS-bounce 64 rows at a time (4 blocks); 1KB runs per wave.
    float* Lf = (float*)SHB;          // 64 x 260 f32 = 66.6 KB
    #pragma unroll
    for (int h = 0; h < 4; ++h) {
        __syncthreads();
        if (wm == (h >> 1)) {
            int mi0 = (h & 1) * 4;
            #pragma unroll
            for (int ni = 0; ni < 4; ni++) {
                int lc = wn * 64 + ni * 16 + l16;
                int colg = n0 + lc;
                float bv = (bias && colg < N) ? bias[colg] : 0.f;
                #pragma unroll
                for (int mi2 = 0; mi2 < 4; mi2++) {
                    int lr = mi2 * 16 + g * 4;
                    #pragma unroll
                    for (int jj = 0; jj < 4; jj++)
                        Lf[(lr + jj) * 260 + lc] = acc[mi0 + mi2][ni][jj] + bv;
                }
            }
        }
        __syncthreads();
        #pragma unroll
        for (int pass = 0; pass < 8; ++pass) {
            int row = pass * 8 + (tid >> 6);
            int c4  = (tid & 63) * 4;
            const float* src = &Lf[row * 260 + c4];
            float* dst = Cout + (size_t)(m0 + h * 64 + row) * N + n0 + c4;
            int col = n0 + c4;
            if (col + 3 < N) {
                *(float2*)dst       = *(const float2*)src;
                *(float2*)(dst + 2) = *(const float2*)(src + 2);
            } else {
                #pragma unroll
                for (int e = 0; e < 4; ++e)
                    if (col + e < N) dst[e] = src[e];
            }
        }
    }
}

// ---------------------------------------------------------------------------
// Flash attention, bf16 MFMA. 3-buffer counted-vmcnt KV pipeline.
// 32-row q-tiles, 2 waves (128 thr), 768 blocks = 3.0/CU exact.
// ---------------------------------------------------------------------------
__global__ __launch_bounds__(128) void attn_mfma(const bf16* __restrict__ qkv,
                                                 const bf16* __restrict__ vt,
                                                 bf16* __restrict__ ao) {
    const int S = 1024, C3 = 2304;
    int wgid = xcd_swz(blockIdx.x, gridDim.x);
    int bh = wgid >> 5, b = bh / 12, h = bh % 12;
    int q0 = (wgid & 31) * 32;
    int tid = threadIdx.x, w = tid >> 6, l = tid & 63;
    int l16 = l & 15, g = l >> 4;

    __shared__ __align__(16) bf16 Ks[3][64 * 64];
    __shared__ __align__(16) bf16 Vs[3][64 * 64];   // [d][key], swizzled rows
    __shared__ __align__(16) bf16 Ps[2][16 * 72];   // per-wave private

    const size_t qbase = ((size_t)(b * S + q0 + w * 16 + l16)) * C3 + h * 64;
    bf16x8 qf[2];
    qf[0] = *(const bf16x8*)&qkv[qbase + g * 8];
    qf[1] = *(const bf16x8*)&qkv[qbase + 32 + g * 8];

    f32x4 o_acc[4];
    f32x4 zero4 = {0.f, 0.f, 0.f, 0.f};
    #pragma unroll
    for (int ni = 0; ni < 4; ni++) o_acc[ni] = zero4;
    float mrow[4] = {-1e30f, -1e30f, -1e30f, -1e30f};
    float lrow[4] = {0.f, 0.f, 0.f, 0.f};
    const float cscale = 0.125f * 1.44269504088896f;   // log2(e)/sqrt(dh)

    int sr0 = w * 32 + (l >> 3);          // +8 per issue
    int cb  = (l & 7) * 16;
    int sc0 = (cb ^ ((sr0 & 7) << 4)) >> 1;
    const bf16* gk0 = qkv + ((size_t)(b * S) + sr0) * C3 + 768 + h * 64 + sc0;
    const bf16* gv0 = vt + ((size_t)bh * 64 + sr0) * 1024 + sc0;
    int ldk0 = (w * 32) * 64;

    auto STAGEKV = [&](int t, int bufi) {
        #pragma unroll
        for (int e = 0; e < 4; e++) {
            gload_lds16(gk0 + (size_t)(t * 64 + e * 8) * C3, &Ks[bufi][ldk0 + e * 8 * 64]);
            gload_lds16(gv0 + t * 64 + (size_t)e * 8 * 1024, &Vs[bufi][ldk0 + e * 8 * 64]);
        }
    };

    STAGEKV(0, 0);
    STAGEKV(1, 1);

    for (int it = 0; it < 16; ++it) {
        if (it == 15) { WAITBAR0(); } else { WAITBAR8(); }
        if (it + 2 < 16) STAGEKV(it + 2, (it + 2) % 3);
        int cur = it % 3;

        f32x4 sfrag[4];
        #pragma unroll
        for (int kf = 0; kf < 4; kf++) {
            sfrag[kf] = zero4;
            int key = kf * 16 + l16;
            #pragma unroll
            for (int kc = 0; kc < 2; kc++) {
                int byteoff = key * 128 + (((kc * 32 + g * 8) * 2) ^ ((key & 7) << 4));
                bf16x8 kb = *(const bf16x8*)((const char*)Ks[cur] + byteoff);
                sfrag[kf] = __builtin_amdgcn_mfma_f32_16x16x32_bf16(qf[kc], kb, sfrag[kf], 0, 0, 0);
            }
        }

        float pv[4][4];
        #pragma unroll
        for (int j = 0; j < 4; j++) {
            float t0 = sfrag[0][j] * cscale, t1 = sfrag[1][j] * cscale;
            float t2 = sfrag[2][j] * cscale, t3 = sfrag[3][j] * cscale;
            float mx = fmaxf(fmaxf(t0, t1), fmaxf(t2, t3));
            mx = red16_max(mx);
            float mnew = fmaxf(mrow[j], mx);
            float r = exp2f(mrow[j] - mnew);
            mrow[j] = mnew;
            float p0 = exp2f(t0 - mnew), p1 = exp2f(t1 - mnew);
            float p2 = exp2f(t2 - mnew), p3 = exp2f(t3 - mnew);
            pv[0][j] = p0; pv[1][j] = p1; pv[2][j] = p2; pv[3][j] = p3;
            float ps = red16_sum(p0 + p1 + p2 + p3);
            lrow[j] = lrow[j] * r + ps;
            #pragma unroll
            for (int ni = 0; ni < 4; ni++) o_acc[ni][j] *= r;
        }

        // P: C-layout -> A-layout via per-wave LDS (no barrier: wave-private)
        #pragma unroll
        for (int kf = 0; kf < 4; kf++)
            #pragma unroll
            for (int j = 0; j < 4; j++)
                Ps[w][(g * 4 + j) * 72 + kf * 16 + l16] = __float2bfloat16(pv[kf][j]);

        #pragma unroll
        for (int kc = 0; kc < 2; kc++) {
            bf16x8 pa = *(const bf16x8*)&Ps[w][l16 * 72 + kc * 32 + g * 8];
            #pragma unroll
            for (int ni = 0; ni < 4; ni++) {
                int d = ni * 16 + l16;
                int byteoff = d * 128 + (((kc * 32 + g * 8) * 2) ^ ((d & 7) << 4));
                bf16x8 vb = *(const bf16x8*)((const char*)Vs[cur] + byteoff);
                o_acc[ni] = __builtin_amdgcn_mfma_f32_16x16x32_bf16(pa, vb, o_acc[ni], 0, 0, 0);
            }
        }
    }

    float linv[4];
    #pragma unroll
    for (int j = 0; j < 4; j++) linv[j] = 1.f / lrow[j];
    #pragma unroll
    for (int ni = 0; ni < 4; ni++) {
        #pragma unroll
        for (int jj = 0; jj < 4; jj++) {
            int row = q0 + w * 16 + g * 4 + jj;
            ao[((size_t)(b * S + row)) * 768 + h * 64 + ni * 16 + l16] =
                __float2bfloat16(o_acc[ni][jj] * linv[jj]);
        }
    }
}

// ---------------------------------------------------------------------------
// Host orchestration
// ---------------------------------------------------------------------------
extern "C" void kernel_launch(void* const* d_in, const int* in_sizes, int n_in,
                              void* d_out, int out_size, void* d_ws, size_t ws_size,
                              hipStream_t stream) {
    const int B = 2, S = 1024, D = 768, L = 12, V = 50258, C = 768, F = 256, MLP = 3072;
    const int M = B * S;

    const int*   indices = (const int*)d_in[0];
    const float* sigma   = (const float*)d_in[1];
    const float* embed   = (const float*)d_in[2];
    const float* t_w1    = (const float*)d_in[3];
    const float* t_b1    = (const float*)d_in[4];
    const float* t_w2    = (const float*)d_in[5];
    const float* t_b2    = (const float*)d_in[6];
    const float* norm1_w = (const float*)d_in[7];
    const float* qkv_w   = (const float*)d_in[8];
    const float* out_w   = (const float*)d_in[9];
    const float* norm2_w = (const float*)d_in[10];
    const float* mlp_w1  = (const float*)d_in[11];
    const float* mlp_b1  = (const float*)d_in[12];
    const float* mlp_w2  = (const float*)d_in[13];
    const float* mlp_b2  = (const float*)d_in[14];
    const float* ada_w   = (const float*)d_in[15];
    const float* ada_b   = (const float*)d_in[16];
    const float* normf_w = (const float*)d_in[17];
    const float* lin_w   = (const float*)d_in[18];
    const float* lin_b   = (const float*)d_in[19];
    const float* adaf_w  = (const float*)d_in[20];
    const float* adaf_b  = (const float*)d_in[21];

    char* p = (char*)d_ws;
    auto alloc = [&](size_t bytes) { char* r = p; p += (bytes + 255) & ~(size_t)255; return r; };

    float* x     = (float*)alloc((size_t)M * D * 4);
    bf16*  xm    = (bf16*) alloc((size_t)M * D * 2);
    bf16*  qkvb  = (bf16*) alloc((size_t)M * 3 * D * 2);
    bf16*  aob   = (bf16*) alloc((size_t)M * D * 2);
    bf16*  hbb   = (bf16*) alloc((size_t)M * MLP * 2);
    bf16*  vtb   = (bf16*) alloc((size_t)24 * 64 * 1024 * 2);
    float* partb = (float*)alloc((size_t)4 * M * D * 4);   // split-K partials
    bf16*  linb  = (bf16*) alloc((size_t)V * D * 2);
    float* tf    = (float*)alloc((size_t)B * F * 4);
    float* h1    = (float*)alloc((size_t)B * C * 4);
    float* cb    = (float*)alloc((size_t)B * C * 4);
    float* ada   = (float*)alloc((size_t)L * B * 6 * D * 4);
    float* adaf  = (float*)alloc((size_t)B * 2 * D * 4);

    const size_t n_qkvw = (size_t)L * 2304 * 768;
    const size_t n_outw = (size_t)L * 768 * 768;
    const size_t n_w1   = (size_t)L * 3072 * 768;
    const size_t n_w2   = (size_t)L * 768 * 3072;
    const size_t per_layer = (size_t)(2304 + 768 + 3072 + 3072) * 768;
    size_t used = (size_t)(p - (char*)d_ws);
    bool all_w = (ws_size - used) >= ((n_qkvw + n_outw + n_w1 + n_w2) * 2 + 1024);

    bf16 *wqkv, *wout, *ww1, *ww2;
    if (all_w) {
        wqkv = (bf16*)alloc(n_qkvw * 2);
        wout = (bf16*)alloc(n_outw * 2);
        ww1  = (bf16*)alloc(n_w1 * 2);
        ww2  = (bf16*)alloc(n_w2 * 2);
    } else {
        bf16* wl = (bf16*)alloc(per_layer * 2);
        wqkv = wl;
        wout = wqkv + (size_t)2304 * 768;
        ww1  = wout + (size_t)768 * 768;
        ww2  = ww1 + (size_t)3072 * 768;
    }

    auto cgrid = [](long n) { return (unsigned)((n / 8 + 255) / 256); };
    dim3 blk(256);

    // prologue
    embed_gather<<<(M * 192) / 256, blk, 0, stream>>>(indices, embed, x);
    tstep_embed<<<1, blk, 0, stream>>>(sigma, tf);
    gemm_rowvec<2><<<(B * C * 64) / 256, blk, 0, stream>>>(tf, t_w1, t_b1, h1, B, C, F);
    gemm_rowvec<2><<<(B * C * 64) / 256, blk, 0, stream>>>(h1, t_w2, t_b2, cb, B, C, C);
    ada_all<<<(L * B * 6 * D * 64) / 256, blk, 0, stream>>>(cb, ada_w, ada_b, ada);
    gemm_rowvec<0><<<(B * 2 * D * 64) / 256, blk, 0, stream>>>(cb, adaf_w, adaf_b, adaf, B, 2 * D, C);
    cvt_bf16<<<cgrid((long)V * D), blk, 0, stream>>>(lin_w, linb, (long)V * D);
    if (all_w) {
        cvt_bf16<<<cgrid((long)n_qkvw), blk, 0, stream>>>(qkv_w, wqkv, (long)n_qkvw);
        cvt_bf16<<<cgrid((long)n_outw), blk, 0, stream>>>(out_w, wout, (long)n_outw);
        cvt_bf16<<<cgrid((long)n_w1),   blk, 0, stream>>>(mlp_w1, ww1, (long)n_w1);
        cvt_bf16<<<cgrid((long)n_w2),   blk, 0, stream>>>(mlp_w2, ww2, (long)n_w2);
    }

    const int MT = M / 128;
    for (int l = 0; l < L; l++) {
        const float* adaL = ada + (size_t)l * B * 6 * D;
        bf16 *wq, *wo, *w1, *w2;
        if (all_w) {
            wq = wqkv + (size_t)l * 2304 * 768;
            wo = wout + (size_t)l * 768 * 768;
            w1 = ww1 + (size_t)l * 3072 * 768;
            w2 = ww2 + (size_t)l * 768 * 3072;
        } else {
            wq = wqkv; wo = wout; w1 = ww1; w2 = ww2;
            cvt_bf16<<<cgrid((long)2304 * 768), blk, 0, stream>>>(qkv_w + (size_t)l * 2304 * 768, wq, (long)2304 * 768);
            cvt_bf16<<<cgrid((long)768 * 768),  blk, 0, stream>>>(out_w + (size_t)l * 768 * 768,  wo, (long)768 * 768);
            cvt_bf16<<<cgrid((long)3072 * 768), blk, 0, stream>>>(mlp_w1 + (size_t)l * 3072 * 768, w1, (long)3072 * 768);
            cvt_bf16<<<cgrid((long)768 * 3072), blk, 0, stream>>>(mlp_w2 + (size_t)l * 768 * 3072, w2, (long)768 * 3072);
        }

        // norm1: layer 0 plain; layers 1.. fold previous layer's mlp2 partials
        if (l == 0) {
            ln_mod<<<M, blk, 0, stream>>>(x, norm1_w, adaL + D, adaL, 6 * D, xm);
        } else {
            const float* adaP = ada + (size_t)(l - 1) * B * 6 * D;
            ln_mod_red<4><<<M, blk, 0, stream>>>(
                x, partb, mlp_b2 + (size_t)(l - 1) * D, adaP + 5 * D, 6 * D,
                norm1_w + (size_t)l * D, adaL + D, adaL, 6 * D, xm);
        }

        // qkv GEMM: q/k -> qkvb, v -> vtb (transposed) fused
        gemm_mfma<0, 3, 1><<<MT * (2304 / 128), blk, 0, stream>>>(
            xm, wq, nullptr, qkvb, vtb, M, 2304, 768);
        attn_mfma<<<768, dim3(128), 0, stream>>>(qkvb, vtb, aob);
        // out-proj: split-K x2 -> partials
        gemm_mfma<0, 4, 2><<<MT * (768 / 128) * 2, blk, 0, stream>>>(
            aob, wo, nullptr, partb, nullptr, M, 768, 768);
        // norm2 folds attn residual
        ln_mod_red<2><<<M, blk, 0, stream>>>(
            x, partb, nullptr, adaL + 2 * D, 6 * D,
            norm2_w + (size_t)l * D, adaL + 4 * D, adaL + 3 * D, 6 * D, xm);

        gemm_mfma<1, 1, 1><<<MT * (3072 / 128), blk, 0, stream>>>(
            xm, w1, mlp_b1 + (size_t)l * MLP, hbb, nullptr, M, 3072, 768);
        // mlp2: split-K x4 -> partials (folded by next norm1 / final norm)
        gemm_mfma<0, 4, 4><<<MT * (768 / 128) * 4, blk, 0, stream>>>(
            hbb, w2, nullptr, partb, nullptr, M, 768, 3072);
    }

    // final: fold last mlp2 residual + normf
    {
        const float* adaP = ada + (size_t)(L - 1) * B * 6 * D;
        ln_mod_red<4><<<M, blk, 0, stream>>>(
            x, partb, mlp_b2 + (size_t)(L - 1) * D, adaP + 5 * D, 6 * D,
            normf_w, adaf + D, adaf, 2 * D, xm);
    }
    // vocab: 256^2 8-wave kernel, 2-buffer pipeline, 2 blocks/CU
    gemm_vocab<<<(M / 256) * ((V + 255) / 256), dim3(512), 0, stream>>>(
        xm, linb, lin_b, (float*)d_out, M, V, 768);
}